// Round 11
// baseline (333.754 us; speedup 1.0000x reference)
//
#include <hip/hip_runtime.h>

// TableEmbed3D: trilinear grid_sample of a [64, 32,32,32] fp32 table at 1e6
// points, align_corners=False, padding_mode='zeros'.
//
// R15 strategy (4 lanes/point x 16 channels; minimize instructions/point):
//  - Evidence: R13 (+21us VALU -> +27us time) and R10 (+latency -> +38us)
//    show ~1:1 marginal instr/latency cost; R5/R11/R13/R14 show bytes,
//    transactions, footprint, store policy all have slack. => embed is
//    issue/latency-coupled; the lever is instructions per point.
//  - 4 lanes/point (was 8): wave carries 16 points -> per-point setup cost
//    halves. Per corner: two adjacent uint4 loads (32 B contiguous/lane;
//    4 lanes cover the 128 B row -> same transaction pattern).
//  - Lane o owns channels [o*16,(o+1)*16) = contiguous 64 B of the output
//    row -> NO shfl epilogue (was 16 shfl + selects). Plain floatx4 stores;
//    NORMAL (cached) stores so L2 merges the 64 B segments into full lines
//    (R11 measured normal == NT on this kernel).
//  - ~18 instr/point vs R6's ~29 (-36%); waves halve; per-thread MLP 2x.
//  - Table layout/transpose identical to R6 ([S][64] bf16, 4 MiB in d_ws).

constexpr int TSZ = 32;
constexpr int S   = TSZ * TSZ * TSZ;  // 32768 spatial cells
constexpr int EMB = 64;               // channels

typedef float floatx4 __attribute__((ext_vector_type(4)));
typedef float f32x2   __attribute__((ext_vector_type(2)));

__device__ __forceinline__ unsigned short f32_to_bf16_rne(float f) {
  unsigned int u = __float_as_uint(f);
  unsigned int lsb = (u >> 16) & 1u;
  u += 0x7FFFu + lsb;  // round to nearest even
  return (unsigned short)(u >> 16);
}

// ---------------------------------------------------------------------------
// Transpose [EMB, S] fp32 -> [S, EMB] bf16 via 64x64 LDS tiles (+1 pad).
__global__ __launch_bounds__(256) void transpose_table_k(
    const float* __restrict__ tab, unsigned short* __restrict__ tabT) {
  __shared__ float tile[EMB][EMB + 1];
  const int s_base = blockIdx.x * 64;
  const int t  = threadIdx.x;
  const int c0 = t & 63;   // inner (coalesced) index
  const int r0 = t >> 6;   // 0..3
#pragma unroll
  for (int i = 0; i < 16; ++i) {
    const int e = r0 + 4 * i;
    tile[e][c0] = tab[(size_t)e * S + (s_base + c0)];  // coalesced read
  }
  __syncthreads();
#pragma unroll
  for (int i = 0; i < 16; ++i) {
    const int s = r0 + 4 * i;
    tabT[(size_t)(s_base + s) * EMB + c0] = f32_to_bf16_rne(tile[c0][s]);
  }
}

// ---------------------------------------------------------------------------
// Main kernel: 4 threads per point, each thread computes 16 channels.
// tabT viewed as uint4* : row lin = elements [lin*8 .. lin*8+7]; lane o reads
// elements lin*8 + 2o and lin*8 + 2o + 1 (32 B = 16 bf16 channels).
__global__ __launch_bounds__(256) void embed_k(
    const float* __restrict__ x, const uint4* __restrict__ tabT,
    float* __restrict__ out, int n) {
  const int gid = blockIdx.x * 256 + threadIdx.x;
  const int pt  = gid >> 2;
  if (pt >= n) return;
  const int o = gid & 3;  // channel sixteenth (16 channels each)

  // clip to [-1,1] then align_corners=False pixel mapping:
  // pix = ((g + 1) * 32 - 1) / 2
  const float gx = fminf(fmaxf(__builtin_nontemporal_load(&x[3 * pt + 0]), -1.f), 1.f);
  const float gy = fminf(fmaxf(__builtin_nontemporal_load(&x[3 * pt + 1]), -1.f), 1.f);
  const float gz = fminf(fmaxf(__builtin_nontemporal_load(&x[3 * pt + 2]), -1.f), 1.f);
  const float px = ((gx + 1.f) * 32.f - 1.f) * 0.5f;
  const float py = ((gy + 1.f) * 32.f - 1.f) * 0.5f;
  const float pz = ((gz + 1.f) * 32.f - 1.f) * 0.5f;

  const float fxf = floorf(px), fyf = floorf(py), fzf = floorf(pz);
  const int ix0 = (int)fxf, iy0 = (int)fyf, iz0 = (int)fzf;
  const float fx = px - fxf, fy = py - fyf, fz = pz - fzf;

  // zeros padding folded into per-axis weights; clamped index irrelevant
  // when the weight is 0.
  float wxe[2], wye[2], wze[2];
  int   ixc[2], iyc[2], izc[2];
  wxe[0] = (ix0 >= 0)      ? (1.f - fx) : 0.f;
  wxe[1] = (ix0 + 1 < TSZ) ? fx         : 0.f;
  ixc[0] = max(ix0, 0);
  ixc[1] = min(ix0 + 1, TSZ - 1);
  wye[0] = (iy0 >= 0)      ? (1.f - fy) : 0.f;
  wye[1] = (iy0 + 1 < TSZ) ? fy         : 0.f;
  iyc[0] = max(iy0, 0);
  iyc[1] = min(iy0 + 1, TSZ - 1);
  wze[0] = (iz0 >= 0)      ? (1.f - fz) : 0.f;
  wze[1] = (iz0 + 1 < TSZ) ? fz         : 0.f;
  izc[0] = max(iz0, 0);
  izc[1] = min(iz0 + 1, TSZ - 1);

  f32x2 a0 = {0.f, 0.f}, a1 = {0.f, 0.f}, a2 = {0.f, 0.f}, a3 = {0.f, 0.f};
  f32x2 a4 = {0.f, 0.f}, a5 = {0.f, 0.f}, a6 = {0.f, 0.f}, a7 = {0.f, 0.f};

#pragma unroll
  for (int dz = 0; dz < 2; ++dz) {
    const int zb = izc[dz] * (TSZ * TSZ);
#pragma unroll
    for (int dy = 0; dy < 2; ++dy) {
      const int   zyb = zb + iyc[dy] * TSZ;
      const float wzy = wze[dz] * wye[dy];
#pragma unroll
      for (int dx = 0; dx < 2; ++dx) {
        const float w   = wzy * wxe[dx];
        const int   lin = zyb + ixc[dx];
        const uint4* rp = &tabT[lin * 8 + o * 2];
        const uint4 qa  = rp[0];  // channels o*16 + 0..7
        const uint4 qb  = rp[1];  // channels o*16 + 8..15
        const f32x2 w2  = {w, w};
        const f32x2 vA0 = {__uint_as_float(qa.x << 16),
                           __uint_as_float(qa.x & 0xFFFF0000u)};
        const f32x2 vA1 = {__uint_as_float(qa.y << 16),
                           __uint_as_float(qa.y & 0xFFFF0000u)};
        const f32x2 vA2 = {__uint_as_float(qa.z << 16),
                           __uint_as_float(qa.z & 0xFFFF0000u)};
        const f32x2 vA3 = {__uint_as_float(qa.w << 16),
                           __uint_as_float(qa.w & 0xFFFF0000u)};
        const f32x2 vB0 = {__uint_as_float(qb.x << 16),
                           __uint_as_float(qb.x & 0xFFFF0000u)};
        const f32x2 vB1 = {__uint_as_float(qb.y << 16),
                           __uint_as_float(qb.y & 0xFFFF0000u)};
        const f32x2 vB2 = {__uint_as_float(qb.z << 16),
                           __uint_as_float(qb.z & 0xFFFF0000u)};
        const f32x2 vB3 = {__uint_as_float(qb.w << 16),
                           __uint_as_float(qb.w & 0xFFFF0000u)};
        a0 = __builtin_elementwise_fma(vA0, w2, a0);
        a1 = __builtin_elementwise_fma(vA1, w2, a1);
        a2 = __builtin_elementwise_fma(vA2, w2, a2);
        a3 = __builtin_elementwise_fma(vA3, w2, a3);
        a4 = __builtin_elementwise_fma(vB0, w2, a4);
        a5 = __builtin_elementwise_fma(vB1, w2, a5);
        a6 = __builtin_elementwise_fma(vB2, w2, a6);
        a7 = __builtin_elementwise_fma(vB3, w2, a7);
      }
    }
  }

  // Epilogue: lane o owns channels [o*16,(o+1)*16) = contiguous 64 B of the
  // output row -> direct stores, no shuffles. Normal (cached) stores: L2
  // merges the per-instruction 16 B segments into full lines (R11 parity).
  float* rowp = out + (size_t)pt * EMB + o * 16;
  const floatx4 s0 = {a0.x, a0.y, a1.x, a1.y};
  const floatx4 s1 = {a2.x, a2.y, a3.x, a3.y};
  const floatx4 s2 = {a4.x, a4.y, a5.x, a5.y};
  const floatx4 s3 = {a6.x, a6.y, a7.x, a7.y};
  *(floatx4*)(rowp + 0)  = s0;
  *(floatx4*)(rowp + 4)  = s1;
  *(floatx4*)(rowp + 8)  = s2;
  *(floatx4*)(rowp + 12) = s3;
}

// ---------------------------------------------------------------------------
// Fallback (workspace too small): 1 thread per (point, channel), reads the
// original [E, S] fp32 layout. Slow but correct.
__global__ __launch_bounds__(256) void embed_fallback_k(
    const float* __restrict__ x, const float* __restrict__ tab,
    float* __restrict__ out, int n) {
  const int gid = blockIdx.x * 256 + threadIdx.x;
  const int pt  = gid >> 6;
  if (pt >= n) return;
  const int e = gid & 63;

  const float gx = fminf(fmaxf(x[3 * pt + 0], -1.f), 1.f);
  const float gy = fminf(fmaxf(x[3 * pt + 1], -1.f), 1.f);
  const float gz = fminf(fmaxf(x[3 * pt + 2], -1.f), 1.f);
  const float px = ((gx + 1.f) * 32.f - 1.f) * 0.5f;
  const float py = ((gy + 1.f) * 32.f - 1.f) * 0.5f;
  const float pz = ((gz + 1.f) * 32.f - 1.f) * 0.5f;

  const float fxf = floorf(px), fyf = floorf(py), fzf = floorf(pz);
  const int ix0 = (int)fxf, iy0 = (int)fyf, iz0 = (int)fzf;
  const float fx = px - fxf, fy = py - fyf, fz = pz - fzf;
  const float wx[2] = {1.f - fx, fx};
  const float wy[2] = {1.f - fy, fy};
  const float wz[2] = {1.f - fz, fz};

  float acc = 0.f;
#pragma unroll
  for (int dz = 0; dz < 2; ++dz) {
    const int  iz  = iz0 + dz;
    const bool bz  = (unsigned)iz < (unsigned)TSZ;
    const int  izc = min(max(iz, 0), TSZ - 1);
#pragma unroll
    for (int dy = 0; dy < 2; ++dy) {
      const int  iy  = iy0 + dy;
      const bool by  = (unsigned)iy < (unsigned)TSZ;
      const int  iyc = min(max(iy, 0), TSZ - 1);
#pragma unroll
      for (int dx = 0; dx < 2; ++dx) {
        const int  ix  = ix0 + dx;
        const bool bx  = (unsigned)ix < (unsigned)TSZ;
        const int  ixc = min(max(ix, 0), TSZ - 1);
        float w = wz[dz] * wy[dy] * wx[dx];
        w = (bx && by && bz) ? w : 0.f;
        const int lin = (izc * TSZ + iyc) * TSZ + ixc;
        acc = fmaf(w, tab[(size_t)e * S + lin], acc);
      }
    }
  }
  out[(size_t)pt * EMB + e] = acc;
}

// ---------------------------------------------------------------------------
extern "C" void kernel_launch(void* const* d_in, const int* in_sizes, int n_in,
                              void* d_out, int out_size, void* d_ws,
                              size_t ws_size, hipStream_t stream) {
  const float* x   = (const float*)d_in[0];
  const float* tab = (const float*)d_in[1];
  float*       out = (float*)d_out;
  const int n = in_sizes[0] / 3;

  const size_t need = (size_t)S * EMB * sizeof(unsigned short);  // 4 MiB
  if (ws_size >= need) {
    unsigned short* tabT = (unsigned short*)d_ws;
    transpose_table_k<<<S / 64, 256, 0, stream>>>(tab, tabT);
    const int total  = n * 4;  // 4 threads per point
    const int blocks = (total + 255) / 256;
    embed_k<<<blocks, 256, 0, stream>>>(x, (const uint4*)tabT, out, n);
  } else {
    const int total  = n * EMB;
    const int blocks = (total + 255) / 256;
    embed_fallback_k<<<blocks, 256, 0, stream>>>(x, tab, out, n);
  }
}

// Round 12
// 308.917 us; speedup vs baseline: 1.0804x; 1.0804x over previous
//
#include <hip/hip_runtime.h>

// TableEmbed3D: trilinear grid_sample of a [64, 32,32,32] fp32 table at 1e6
// points, align_corners=False, padding_mode='zeros'.
//
// R16 = REVERT to R6, the measured optimum (309.6 us). Evidence ledger from
// seven single-variable experiments (delta vs 309.6):
//   R5  XCD channel split (L2 footprint/2)      +27
//   R10 NT table gathers (cache-tier demotion)  +38
//   R11 normal stores (vs NT)                   +4 (noise)
//   R13 int8 table (-50% gather bytes, +VALU)   +27
//   R14 zero-weight corner skip (-40% requests) +6 (noise)
//   R15 4 lanes/pt (-36% instr/pt)              +24
// Structural accounting: 309.6 = fill ~163 (harness) + transpose ~3 +
// embed ~143, where embed ~= 1.02 GB random 128B-line L2 gathers at the
// chip's scattered-line service rate (~8-10 TB/s -> 102-128 us; every byte
// of every fetched line is consumed) + 256 MB HBM writes (41 us, partially
// overlapped). Channel-major LDS alternative loses to its own transpose
// pass (~82 us) + weight re-read traffic. This is the practical floor.
//
// Kernel structure:
//  - table transposed+quantized to [S=32768][64] bf16 in d_ws (4 MiB).
//  - embed: 8 lanes per point, each lane owns 8 channels. Every corner gather
//    is one dense uint4 (16 B) load; 8 lanes cover the full 128 B row.
//  - store epilogue: shfl-redistribute so each NT store instruction writes a
//    CONTIGUOUS 128 B line per point.
//  - zeros padding folded into per-axis weights; packed v_pk_fma_f32;
//    NT loads for x.

constexpr int TSZ = 32;
constexpr int S   = TSZ * TSZ * TSZ;  // 32768 spatial cells
constexpr int EMB = 64;               // channels

typedef float floatx4 __attribute__((ext_vector_type(4)));
typedef float f32x2   __attribute__((ext_vector_type(2)));

__device__ __forceinline__ unsigned short f32_to_bf16_rne(float f) {
  unsigned int u = __float_as_uint(f);
  unsigned int lsb = (u >> 16) & 1u;
  u += 0x7FFFu + lsb;  // round to nearest even
  return (unsigned short)(u >> 16);
}

// ---------------------------------------------------------------------------
// Transpose [EMB, S] fp32 -> [S, EMB] bf16 via 64x64 LDS tiles (+1 pad).
// grid: S/64 blocks of 256 threads.
__global__ __launch_bounds__(256) void transpose_table_k(
    const float* __restrict__ tab, unsigned short* __restrict__ tabT) {
  __shared__ float tile[EMB][EMB + 1];
  const int s_base = blockIdx.x * 64;
  const int t  = threadIdx.x;
  const int c0 = t & 63;   // inner (coalesced) index
  const int r0 = t >> 6;   // 0..3
#pragma unroll
  for (int i = 0; i < 16; ++i) {
    const int e = r0 + 4 * i;
    tile[e][c0] = tab[(size_t)e * S + (s_base + c0)];  // coalesced read
  }
  __syncthreads();
#pragma unroll
  for (int i = 0; i < 16; ++i) {
    const int s = r0 + 4 * i;
    tabT[(size_t)(s_base + s) * EMB + c0] = f32_to_bf16_rne(tile[c0][s]);
  }
}

// ---------------------------------------------------------------------------
// Main kernel: 8 threads per point, each thread computes 8 channels.
// tabT viewed as uint4* : row lin occupies elements [lin*8 .. lin*8+7];
// lane c8 reads element lin*8 + c8 (16 B = 8 bf16 channels).
__global__ __launch_bounds__(256) void embed_k(
    const float* __restrict__ x, const uint4* __restrict__ tabT,
    float* __restrict__ out, int n) {
  const int gid = blockIdx.x * 256 + threadIdx.x;
  const int pt  = gid >> 3;
  if (pt >= n) return;
  const int c8 = gid & 7;  // channel octet (8 channels each)

  // clip to [-1,1] then align_corners=False pixel mapping:
  // pix = ((g + 1) * 32 - 1) / 2
  const float gx = fminf(fmaxf(__builtin_nontemporal_load(&x[3 * pt + 0]), -1.f), 1.f);
  const float gy = fminf(fmaxf(__builtin_nontemporal_load(&x[3 * pt + 1]), -1.f), 1.f);
  const float gz = fminf(fmaxf(__builtin_nontemporal_load(&x[3 * pt + 2]), -1.f), 1.f);
  const float px = ((gx + 1.f) * 32.f - 1.f) * 0.5f;
  const float py = ((gy + 1.f) * 32.f - 1.f) * 0.5f;
  const float pz = ((gz + 1.f) * 32.f - 1.f) * 0.5f;

  const float fxf = floorf(px), fyf = floorf(py), fzf = floorf(pz);
  const int ix0 = (int)fxf, iy0 = (int)fyf, iz0 = (int)fzf;
  const float fx = px - fxf, fy = py - fyf, fz = pz - fzf;

  // zeros padding factorized into per-axis weights: w*inb =
  // (wz*bz)*(wy*by)*(wx*bx). Clamped index is irrelevant when weight==0.
  float wxe[2], wye[2], wze[2];
  int   ixc[2], iyc[2], izc[2];
  wxe[0] = (ix0 >= 0)       ? (1.f - fx) : 0.f;
  wxe[1] = (ix0 + 1 < TSZ)  ? fx         : 0.f;
  ixc[0] = max(ix0, 0);
  ixc[1] = min(ix0 + 1, TSZ - 1);
  wye[0] = (iy0 >= 0)       ? (1.f - fy) : 0.f;
  wye[1] = (iy0 + 1 < TSZ)  ? fy         : 0.f;
  iyc[0] = max(iy0, 0);
  iyc[1] = min(iy0 + 1, TSZ - 1);
  wze[0] = (iz0 >= 0)       ? (1.f - fz) : 0.f;
  wze[1] = (iz0 + 1 < TSZ)  ? fz         : 0.f;
  izc[0] = max(iz0, 0);
  izc[1] = min(iz0 + 1, TSZ - 1);

  f32x2 a01 = {0.f, 0.f}, a23 = {0.f, 0.f}, a45 = {0.f, 0.f}, a67 = {0.f, 0.f};

#pragma unroll
  for (int dz = 0; dz < 2; ++dz) {
    const int zb = izc[dz] * (TSZ * TSZ);
#pragma unroll
    for (int dy = 0; dy < 2; ++dy) {
      const int   zyb = zb + iyc[dy] * TSZ;
      const float wzy = wze[dz] * wye[dy];
#pragma unroll
      for (int dx = 0; dx < 2; ++dx) {
        const float w   = wzy * wxe[dx];
        const int   lin = zyb + ixc[dx];
        const uint4 q   = tabT[lin * 8 + c8];
        const f32x2 w2  = {w, w};
        const f32x2 v01 = {__uint_as_float(q.x << 16),
                           __uint_as_float(q.x & 0xFFFF0000u)};
        const f32x2 v23 = {__uint_as_float(q.y << 16),
                           __uint_as_float(q.y & 0xFFFF0000u)};
        const f32x2 v45 = {__uint_as_float(q.z << 16),
                           __uint_as_float(q.z & 0xFFFF0000u)};
        const f32x2 v67 = {__uint_as_float(q.w << 16),
                           __uint_as_float(q.w & 0xFFFF0000u)};
        a01 = __builtin_elementwise_fma(v01, w2, a01);
        a23 = __builtin_elementwise_fma(v23, w2, a23);
        a45 = __builtin_elementwise_fma(v45, w2, a45);
        a67 = __builtin_elementwise_fma(v67, w2, a67);
      }
    }
  }

  // -------------------------------------------------------------------------
  // Epilogue: redistribute so each NT store instruction writes a CONTIGUOUS
  // 128 B per point. Store 1 covers row bytes [0,128): lane c8 writes floats
  // [c8*4, c8*4+4), owned by lane grp+(c8>>1) at element (c8&1)*4+j.
  // Store 2 covers bytes [128,256) analogously from lanes grp+4+(c8>>1).
  const float accv[8] = {a01.x, a01.y, a23.x, a23.y, a45.x, a45.y, a67.x, a67.y};
  const int lane = threadIdx.x & 63;
  const int grp  = lane & ~7;            // 8-lane point group within the wave
  const int src1 = grp + (c8 >> 1);
  const int src2 = grp + 4 + (c8 >> 1);
  const bool hi  = (c8 & 1) != 0;
  float o0[4], o1[4];
#pragma unroll
  for (int j = 0; j < 4; ++j) {
    const float aj = __shfl(accv[j],     src1, 64);
    const float bj = __shfl(accv[4 + j], src1, 64);
    o0[j] = hi ? bj : aj;
    const float cj = __shfl(accv[j],     src2, 64);
    const float dj = __shfl(accv[4 + j], src2, 64);
    o1[j] = hi ? dj : cj;
  }
  const floatx4 s0 = {o0[0], o0[1], o0[2], o0[3]};
  const floatx4 s1 = {o1[0], o1[1], o1[2], o1[3]};
  float* rowp = out + (size_t)pt * EMB;  // 256 B output row
  __builtin_nontemporal_store(s0, (floatx4*)(rowp + c8 * 4));       // [0,128)
  __builtin_nontemporal_store(s1, (floatx4*)(rowp + 32 + c8 * 4));  // [128,256)
}

// ---------------------------------------------------------------------------
// Fallback (workspace too small): 1 thread per (point, channel), reads the
// original [E, S] fp32 layout. Slow but correct.
__global__ __launch_bounds__(256) void embed_fallback_k(
    const float* __restrict__ x, const float* __restrict__ tab,
    float* __restrict__ out, int n) {
  const int gid = blockIdx.x * 256 + threadIdx.x;
  const int pt  = gid >> 6;
  if (pt >= n) return;
  const int e = gid & 63;

  const float gx = fminf(fmaxf(x[3 * pt + 0], -1.f), 1.f);
  const float gy = fminf(fmaxf(x[3 * pt + 1], -1.f), 1.f);
  const float gz = fminf(fmaxf(x[3 * pt + 2], -1.f), 1.f);
  const float px = ((gx + 1.f) * 32.f - 1.f) * 0.5f;
  const float py = ((gy + 1.f) * 32.f - 1.f) * 0.5f;
  const float pz = ((gz + 1.f) * 32.f - 1.f) * 0.5f;

  const float fxf = floorf(px), fyf = floorf(py), fzf = floorf(pz);
  const int ix0 = (int)fxf, iy0 = (int)fyf, iz0 = (int)fzf;
  const float fx = px - fxf, fy = py - fyf, fz = pz - fzf;
  const float wx[2] = {1.f - fx, fx};
  const float wy[2] = {1.f - fy, fy};
  const float wz[2] = {1.f - fz, fz};

  float acc = 0.f;
#pragma unroll
  for (int dz = 0; dz < 2; ++dz) {
    const int  iz  = iz0 + dz;
    const bool bz  = (unsigned)iz < (unsigned)TSZ;
    const int  izc = min(max(iz, 0), TSZ - 1);
#pragma unroll
    for (int dy = 0; dy < 2; ++dy) {
      const int  iy  = iy0 + dy;
      const bool by  = (unsigned)iy < (unsigned)TSZ;
      const int  iyc = min(max(iy, 0), TSZ - 1);
#pragma unroll
      for (int dx = 0; dx < 2; ++dx) {
        const int  ix  = ix0 + dx;
        const bool bx  = (unsigned)ix < (unsigned)TSZ;
        const int  ixc = min(max(ix, 0), TSZ - 1);
        float w = wz[dz] * wy[dy] * wx[dx];
        w = (bx && by && bz) ? w : 0.f;
        const int lin = (izc * TSZ + iyc) * TSZ + ixc;
        acc = fmaf(w, tab[(size_t)e * S + lin], acc);
      }
    }
  }
  out[(size_t)pt * EMB + e] = acc;
}

// ---------------------------------------------------------------------------
extern "C" void kernel_launch(void* const* d_in, const int* in_sizes, int n_in,
                              void* d_out, int out_size, void* d_ws,
                              size_t ws_size, hipStream_t stream) {
  const float* x   = (const float*)d_in[0];
  const float* tab = (const float*)d_in[1];
  float*       out = (float*)d_out;
  const int n = in_sizes[0] / 3;

  const size_t need = (size_t)S * EMB * sizeof(unsigned short);  // 4 MiB
  if (ws_size >= need) {
    unsigned short* tabT = (unsigned short*)d_ws;
    transpose_table_k<<<S / 64, 256, 0, stream>>>(tab, tabT);
    const int total  = n * 8;  // 8 threads per point
    const int blocks = (total + 255) / 256;
    embed_k<<<blocks, 256, 0, stream>>>(x, (const uint4*)tabT, out, n);
  } else {
    const int total  = n * EMB;
    const int blocks = (total + 255) / 256;
    embed_fallback_k<<<blocks, 256, 0, stream>>>(x, tab, out, n);
  }
}